// Round 1
// baseline (320.849 us; speedup 1.0000x reference)
//
#include <hip/hip_runtime.h>

// CorrelationCost (tfa), kernel_size=1, stride=1, max_displacement=pad=4,
// channels_first. B=4, C=128, H=128, W=256 -> out [4, 81, 128, 256] fp32.
//
// out[b, dy*9+dx, y, x] = (1/C) * sum_c prv[b,c,y,x] * nxt[b,c,y+dy-4,x+dx-4]
// (nxt zero-padded by 4 on each spatial side).

#define SR 4
#define ND 9          // 2*SR+1
#define BB 4
#define CC 128
#define HH 128
#define WW 256
#define HW (HH * WW)

__global__ __launch_bounds__(256) void costvol_kernel(
    const float* __restrict__ prv,
    const float* __restrict__ nxt,
    float* __restrict__ out)
{
    // XCD-chunked bijective swizzle: gridDim.x = 1152 is divisible by 8.
    const int nwg  = gridDim.x;
    const int cpx  = nwg >> 3;               // blocks per XCD chunk
    const int orig = blockIdx.x;
    const int wid  = (orig & 7) * cpx + (orig >> 3);

    // Work decomposition: dy fastest (so same-(b,y) blocks are L2-local),
    // then y-quad, then batch.
    const int dy = wid % ND;
    const int r  = wid / ND;
    const int y4 = r & 31;                   // 32 quads of 4 rows
    const int b  = r >> 5;

    const int tid  = threadIdx.x;
    const int ry   = tid >> 6;               // row within quad (wave id)
    const int lane = tid & 63;
    const int x0   = lane << 2;              // 4 x-pixels per lane
    const int y    = (y4 << 2) + ry;
    const int yp   = y + dy - SR;            // nxt source row

    float* outp = out + (((size_t)b * (ND * ND) + (size_t)dy * ND) * HH + y) * WW + x0;

    if (yp < 0 || yp >= HH) {
        // Entire displacement row is zero-padded: emit zeros (d_out is poisoned).
        const float4 z = make_float4(0.f, 0.f, 0.f, 0.f);
        #pragma unroll
        for (int dx = 0; dx < ND; ++dx)
            *reinterpret_cast<float4*>(outp + (size_t)dx * HW) = z;
        return;
    }

    const float* pp  = prv + ((size_t)b * CC * HH + y)  * WW + x0;
    const float* np0 = nxt + ((size_t)b * CC * HH + yp) * WW;

    float acc[ND][4];
    #pragma unroll
    for (int dx = 0; dx < ND; ++dx)
        #pragma unroll
        for (int j = 0; j < 4; ++j)
            acc[dx][j] = 0.f;

    // Horizontal zero-pad aligns exactly with float4 boundaries:
    // window [x0-4, x0+8) = three float4s; only lane 0's left quad and
    // lane 63's right quad are fully out of bounds.
    const bool lft = (x0 >= 4);
    const bool rgt = (x0 <= WW - 8);
    const float4 zero4 = make_float4(0.f, 0.f, 0.f, 0.f);

    for (int c = 0; c < CC; ++c) {
        const float* prow = pp  + (size_t)c * HW;
        const float* nrow = np0 + (size_t)c * HW;

        const float4 p4 = *reinterpret_cast<const float4*>(prow);
        const float4 na = lft ? *reinterpret_cast<const float4*>(nrow + x0 - 4) : zero4;
        const float4 nb = *reinterpret_cast<const float4*>(nrow + x0);
        const float4 nc = rgt ? *reinterpret_cast<const float4*>(nrow + x0 + 4) : zero4;

        const float p[4]  = {p4.x, p4.y, p4.z, p4.w};
        const float n[12] = {na.x, na.y, na.z, na.w,
                             nb.x, nb.y, nb.z, nb.w,
                             nc.x, nc.y, nc.z, nc.w};

        #pragma unroll
        for (int dx = 0; dx < ND; ++dx)
            #pragma unroll
            for (int j = 0; j < 4; ++j)
                acc[dx][j] = fmaf(p[j], n[dx + j], acc[dx][j]);
    }

    const float invc = 1.0f / (float)CC;
    #pragma unroll
    for (int dx = 0; dx < ND; ++dx) {
        const float4 o = make_float4(acc[dx][0] * invc, acc[dx][1] * invc,
                                     acc[dx][2] * invc, acc[dx][3] * invc);
        *reinterpret_cast<float4*>(outp + (size_t)dx * HW) = o;
    }
}

extern "C" void kernel_launch(void* const* d_in, const int* in_sizes, int n_in,
                              void* d_out, int out_size, void* d_ws, size_t ws_size,
                              hipStream_t stream) {
    const float* prv = (const float*)d_in[0];
    const float* nxt = (const float*)d_in[1];
    float* out = (float*)d_out;

    const int nblocks = BB * (HH / 4) * ND;  // 4 * 32 * 9 = 1152
    costvol_kernel<<<nblocks, 256, 0, stream>>>(prv, nxt, out);
}

// Round 2
// 83.582 us; speedup vs baseline: 3.8387x; 3.8387x over previous
//
#include <hip/hip_runtime.h>

// CorrelationCost (tfa), kernel_size=1, stride=1, max_displacement=pad=4,
// channels_first. B=4, C=128, H=128, W=256 -> out [4, 81, 128, 256] fp32.
//
// out[b, dy*9+dx, y, x] = (1/C) * sum_c prv[b,c,y,x] * nxt[b,c,y+dy-4,x+dx-4]
//
// R1: latency-bound (VALUBusy 10.7%). Fixes:
//  - register double-buffered c-loop (prefetch next channel's quads)
//  - na/nc quads via ds_bpermute from lane+-1 instead of 2 extra global loads

#define SR 4
#define ND 9          // 2*SR+1
#define BB 4
#define CC 128
#define HH 128
#define WW 256
#define HW (HH * WW)

__global__ __launch_bounds__(256) void costvol_kernel(
    const float* __restrict__ prv,
    const float* __restrict__ nxt,
    float* __restrict__ out)
{
    // XCD-chunked bijective swizzle: gridDim.x = 1152 is divisible by 8.
    const int nwg  = gridDim.x;
    const int cpx  = nwg >> 3;
    const int orig = blockIdx.x;
    const int wid  = (orig & 7) * cpx + (orig >> 3);

    // dy fastest so the 9 dy-blocks sharing (b,y) rows are L2-local.
    const int dy = wid % ND;
    const int r  = wid / ND;
    const int y4 = r & 31;
    const int b  = r >> 5;

    const int tid  = threadIdx.x;
    const int ry   = tid >> 6;               // wave id = row within quad
    const int lane = tid & 63;
    const int x0   = lane << 2;              // 4 x-pixels per lane
    const int y    = (y4 << 2) + ry;
    const int yp   = y + dy - SR;

    float* outp = out + (((size_t)b * (ND * ND) + (size_t)dy * ND) * HH + y) * WW + x0;

    if (yp < 0 || yp >= HH) {
        const float4 z = make_float4(0.f, 0.f, 0.f, 0.f);
        #pragma unroll
        for (int dx = 0; dx < ND; ++dx)
            *reinterpret_cast<float4*>(outp + (size_t)dx * HW) = z;
        return;
    }

    const float* pp = prv + ((size_t)b * CC * HH + y)  * WW + x0;  // prv quad
    const float* nn = nxt + ((size_t)b * CC * HH + yp) * WW + x0;  // nxt mid quad

    // Cross-lane shift addresses (byte index = lane*4 within the wave).
    const int addr_m = ((lane - 1) & 63) << 2;   // pull from lane-1 (na)
    const int addr_p = ((lane + 1) & 63) << 2;   // pull from lane+1 (nc)
    const bool has_l = (lane != 0);              // x0-4 >= 0
    const bool has_r = (lane != 63);             // x0+7 <= W-1

    float acc[ND][4];
    #pragma unroll
    for (int dx = 0; dx < ND; ++dx)
        #pragma unroll
        for (int j = 0; j < 4; ++j)
            acc[dx][j] = 0.f;

    auto compute = [&](const float4& p4, const float4& nb4) {
        const float p[4]  = {p4.x, p4.y, p4.z, p4.w};
        const float nb[4] = {nb4.x, nb4.y, nb4.z, nb4.w};
        float n[12];
        #pragma unroll
        for (int j = 0; j < 4; ++j) {
            const int   s  = __float_as_int(nb[j]);
            const float vm = __int_as_float(__builtin_amdgcn_ds_bpermute(addr_m, s));
            const float vp = __int_as_float(__builtin_amdgcn_ds_bpermute(addr_p, s));
            n[j]     = has_l ? vm : 0.0f;
            n[4 + j] = nb[j];
            n[8 + j] = has_r ? vp : 0.0f;
        }
        #pragma unroll
        for (int dx = 0; dx < ND; ++dx)
            #pragma unroll
            for (int j = 0; j < 4; ++j)
                acc[dx][j] = fmaf(p[j], n[dx + j], acc[dx][j]);
    };

    // Register double-buffered channel loop: loads for c+1 are in flight
    // while c's 36 FMAs issue.
    const float* ppc = pp;
    const float* nnc = nn;
    float4 pA = *reinterpret_cast<const float4*>(ppc);
    float4 nA = *reinterpret_cast<const float4*>(nnc);
    ppc += HW; nnc += HW;

    for (int c = 0; c < CC - 2; c += 2) {
        const float4 pB = *reinterpret_cast<const float4*>(ppc);
        const float4 nB = *reinterpret_cast<const float4*>(nnc);
        ppc += HW; nnc += HW;
        compute(pA, nA);
        pA = *reinterpret_cast<const float4*>(ppc);
        nA = *reinterpret_cast<const float4*>(nnc);
        ppc += HW; nnc += HW;
        compute(pB, nB);
    }
    {   // c = 126, 127
        const float4 pB = *reinterpret_cast<const float4*>(ppc);
        const float4 nB = *reinterpret_cast<const float4*>(nnc);
        compute(pA, nA);
        compute(pB, nB);
    }

    const float invc = 1.0f / (float)CC;
    #pragma unroll
    for (int dx = 0; dx < ND; ++dx) {
        const float4 o = make_float4(acc[dx][0] * invc, acc[dx][1] * invc,
                                     acc[dx][2] * invc, acc[dx][3] * invc);
        *reinterpret_cast<float4*>(outp + (size_t)dx * HW) = o;
    }
}

extern "C" void kernel_launch(void* const* d_in, const int* in_sizes, int n_in,
                              void* d_out, int out_size, void* d_ws, size_t ws_size,
                              hipStream_t stream) {
    const float* prv = (const float*)d_in[0];
    const float* nxt = (const float*)d_in[1];
    float* out = (float*)d_out;

    const int nblocks = BB * (HH / 4) * ND;  // 4 * 32 * 9 = 1152
    costvol_kernel<<<nblocks, 256, 0, stream>>>(prv, nxt, out);
}

// Round 4
// 71.497 us; speedup vs baseline: 4.4876x; 1.1690x over previous
//
#include <hip/hip_runtime.h>

// CorrelationCost (tfa), kernel_size=1, stride=1, max_displacement=pad=4,
// channels_first. B=4, C=128, H=128, W=256 -> out [4, 81, 128, 256] fp32.
//
// out[b, dy*9+dx, y, x] = (1/C) * sum_c prv[b,c,y,x] * nxt[b,c,y+dy-4,x+dx-4]
//
// R3 failed: cross-lane LDS window reads were hoisted past the row writes by
// the compiler (per-thread no-alias). R4: __threadfence_block() after each
// FMA burst pins write->read order (and is ~free there), plus a 4-deep
// register rotation so ds_writes/FMAs consume globals loaded 2-3 phases ago.

#define SR 4
#define ND 9          // 2*SR+1
#define BB 4
#define CC 128
#define HH 128
#define WW 256
#define HW (HH * WW)
#define PADW (WW + 8)

__global__ __launch_bounds__(256) void costvol_kernel(
    const float* __restrict__ prv,
    const float* __restrict__ nxt,
    float* __restrict__ out)
{
    // [wave][buf][padded row] : 4*2*264*4 = 8448 B
    __shared__ float lds[4][2][PADW];

    // XCD-chunked bijective swizzle (1152 % 8 == 0).
    const int nwg  = gridDim.x;
    const int cpx  = nwg >> 3;
    const int orig = blockIdx.x;
    const int wid  = (orig & 7) * cpx + (orig >> 3);

    // dy fastest: the 9 dy-blocks sharing (b,y) rows are L2-local.
    const int dy = wid % ND;
    const int r  = wid / ND;
    const int y4 = r & 31;
    const int b  = r >> 5;

    const int tid  = threadIdx.x;
    const int ry   = tid >> 6;               // wave id = row within quad
    const int lane = tid & 63;
    const int x0   = lane << 2;              // 4 x-pixels per lane
    const int y    = (y4 << 2) + ry;
    const int yp   = y + dy - SR;

    float* outp = out + (((size_t)b * (ND * ND) + (size_t)dy * ND) * HH + y) * WW + x0;

    if (yp < 0 || yp >= HH) {
        const float4 z = make_float4(0.f, 0.f, 0.f, 0.f);
        #pragma unroll
        for (int dx = 0; dx < ND; ++dx)
            *reinterpret_cast<float4*>(outp + (size_t)dx * HW) = z;
        return;
    }

    const float* pg = prv + ((size_t)b * CC * HH + y)  * WW + x0;
    const float* ng = nxt + ((size_t)b * CC * HH + yp) * WW + x0;

    // Zero the 4-float pads at both ends of both buffers, once.
    if (lane < 2) {
        const float4 z = make_float4(0.f, 0.f, 0.f, 0.f);
        *reinterpret_cast<float4*>(&lds[ry][lane][0])      = z;
        *reinterpret_cast<float4*>(&lds[ry][lane][WW + 4]) = z;
    }

    float acc[ND][4];
    #pragma unroll
    for (int dx = 0; dx < ND; ++dx)
        #pragma unroll
        for (int j = 0; j < 4; ++j)
            acc[dx][j] = 0.f;

    auto step = [&](const float4& p4, const float4& wl,
                    const float4& own, const float4& wr) {
        const float p[4]  = {p4.x, p4.y, p4.z, p4.w};
        const float n[12] = {wl.x,  wl.y,  wl.z,  wl.w,
                             own.x, own.y, own.z, own.w,
                             wr.x,  wr.y,  wr.z,  wr.w};
        #pragma unroll
        for (int dx = 0; dx < ND; ++dx)
            #pragma unroll
            for (int j = 0; j < 4; ++j)
                acc[dx][j] = fmaf(p[j], n[dx + j], acc[dx][j]);
    };

    // LDS addresses (byte 16*lane based -> all 16B-aligned, conflict-free).
    float4* st0 = reinterpret_cast<float4*>(&lds[ry][0][4 + x0]);
    float4* st1 = reinterpret_cast<float4*>(&lds[ry][1][4 + x0]);
    const float4* rl0 = reinterpret_cast<const float4*>(&lds[ry][0][x0]);
    const float4* rr0 = reinterpret_cast<const float4*>(&lds[ry][0][x0 + 8]);
    const float4* rl1 = reinterpret_cast<const float4*>(&lds[ry][1][x0]);
    const float4* rr1 = reinterpret_cast<const float4*>(&lds[ry][1][x0 + 8]);

    #define GLD(dst_p, dst_n) do { \
        dst_p = *reinterpret_cast<const float4*>(pg); pg += HW; \
        dst_n = *reinterpret_cast<const float4*>(ng); ng += HW; } while (0)

    // Prologue: channels 0..2 in flight; channel 0 staged to buf0.
    float4 pA, nA, pB, nB, pC, nC, pD, nD;
    GLD(pA, nA);
    GLD(pB, nB);
    GLD(pC, nC);
    *st0 = nA;
    __threadfence_block();

    // Steady state entering phase c: regs A=c, B=c+1, C=c+2; buf[c&1] = row c.
    float4 wl, wr;
    for (int c = 0; c < CC - 4; c += 4) {
        // phase c (buf0)
        wl = *rl0; wr = *rr0;
        *st1 = nB;                       // stage c+1 (loaded 2 phases ago)
        GLD(pD, nD);                     // c+3
        step(pA, wl, nA, wr);
        __threadfence_block();
        // phase c+1 (buf1)
        wl = *rl1; wr = *rr1;
        *st0 = nC;                       // stage c+2
        GLD(pA, nA);                     // c+4
        step(pB, wl, nB, wr);
        __threadfence_block();
        // phase c+2 (buf0)
        wl = *rl0; wr = *rr0;
        *st1 = nD;                       // stage c+3
        GLD(pB, nB);                     // c+5
        step(pC, wl, nC, wr);
        __threadfence_block();
        // phase c+3 (buf1)
        wl = *rl1; wr = *rr1;
        *st0 = nA;                       // stage c+4
        GLD(pC, nC);                     // c+6
        step(pD, wl, nD, wr);
        __threadfence_block();
    }
    // Tail: channels 124..127 (A=124, B=125, C=126; buf0 = row 124).
    {
        wl = *rl0; wr = *rr0;
        *st1 = nB;
        GLD(pD, nD);                     // 127
        step(pA, wl, nA, wr);
        __threadfence_block();
        wl = *rl1; wr = *rr1;
        *st0 = nC;
        step(pB, wl, nB, wr);
        __threadfence_block();
        wl = *rl0; wr = *rr0;
        *st1 = nD;
        step(pC, wl, nC, wr);
        __threadfence_block();
        wl = *rl1; wr = *rr1;
        step(pD, wl, nD, wr);
    }
    #undef GLD

    const float invc = 1.0f / (float)CC;
    #pragma unroll
    for (int dx = 0; dx < ND; ++dx) {
        const float4 o = make_float4(acc[dx][0] * invc, acc[dx][1] * invc,
                                     acc[dx][2] * invc, acc[dx][3] * invc);
        *reinterpret_cast<float4*>(outp + (size_t)dx * HW) = o;
    }
}

extern "C" void kernel_launch(void* const* d_in, const int* in_sizes, int n_in,
                              void* d_out, int out_size, void* d_ws, size_t ws_size,
                              hipStream_t stream) {
    const float* prv = (const float*)d_in[0];
    const float* nxt = (const float*)d_in[1];
    float* out = (float*)d_out;

    const int nblocks = BB * (HH / 4) * ND;  // 4 * 32 * 9 = 1152
    costvol_kernel<<<nblocks, 256, 0, stream>>>(prv, nxt, out);
}

// Round 6
// 57.629 us; speedup vs baseline: 5.5675x; 1.2406x over previous
//
#include <hip/hip_runtime.h>

// CorrelationCost (tfa), kernel_size=1, stride=1, max_displacement=pad=4,
// channels_first. B=4, C=128, H=128, W=256 -> out [4, 81, 128, 256] fp32.
//
// out[b, dy*9+dx, y, x] = (1/C) * sum_c prv[b,c,y,x] * nxt[b,c,y+dy-4,x+dx-4]
//
// R5 (fixed): process channel PAIRS via v_dot2_f32_f16 (fp32 accumulate).
// Inputs converted on the fly with v_cvt_pkrtz_f16_f32; nxt rows staged in
// LDS as packed half2(c, c+1) per pixel. Per channel: VALU math and LDS
// traffic halve; global bytes unchanged. Same 4-slot rotation + fence
// schedule as R4 (proven race-free).
// R5 compile fix: h2 must be __fp16-based (builtin return type), not _Float16.

#define SR 4
#define ND 9          // 2*SR+1
#define BB 4
#define CC 128
#define HH 128
#define WW 256
#define HW (HH * WW)
#define PADW (WW + 8)

typedef __fp16 h2 __attribute__((ext_vector_type(2)));

static __device__ __forceinline__ h2 pk(float lo, float hi) {
    return __builtin_amdgcn_cvt_pkrtz(lo, hi);   // v_cvt_pkrtz_f16_f32
}
static __device__ __forceinline__ h2 as_h2(unsigned int u) {
    union { unsigned int u; h2 h; } v; v.u = u; return v.h;
}
static __device__ __forceinline__ unsigned int as_u32(h2 h) {
    union { unsigned int u; h2 h; } v; v.h = h; return v.u;
}

__global__ __launch_bounds__(256) void costvol_kernel(
    const float* __restrict__ prv,
    const float* __restrict__ nxt,
    float* __restrict__ out)
{
    // [wave][buf][padded row of half2-pairs] : 4*2*264*4 = 8448 B
    __shared__ unsigned int lds[4][2][PADW];

    // XCD-chunked bijective swizzle (1152 % 8 == 0).
    const int nwg  = gridDim.x;
    const int cpx  = nwg >> 3;
    const int orig = blockIdx.x;
    const int wid  = (orig & 7) * cpx + (orig >> 3);

    // dy fastest: the 9 dy-blocks sharing (b,y) rows are L2-local.
    const int dy = wid % ND;
    const int r  = wid / ND;
    const int y4 = r & 31;
    const int b  = r >> 5;

    const int tid  = threadIdx.x;
    const int ry   = tid >> 6;               // wave id = row within quad
    const int lane = tid & 63;
    const int x0   = lane << 2;              // 4 x-pixels per lane
    const int y    = (y4 << 2) + ry;
    const int yp   = y + dy - SR;

    float* outp = out + (((size_t)b * (ND * ND) + (size_t)dy * ND) * HH + y) * WW + x0;

    if (yp < 0 || yp >= HH) {
        const float4 z = make_float4(0.f, 0.f, 0.f, 0.f);
        #pragma unroll
        for (int dx = 0; dx < ND; ++dx)
            *reinterpret_cast<float4*>(outp + (size_t)dx * HW) = z;
        return;
    }

    const float* pg = prv + ((size_t)b * CC * HH + y)  * WW + x0;
    const float* ng = nxt + ((size_t)b * CC * HH + yp) * WW + x0;

    // Zero the 4-element pads at both ends of both buffers, once.
    if (lane < 2) {
        const uint4 z = make_uint4(0u, 0u, 0u, 0u);
        *reinterpret_cast<uint4*>(&lds[ry][lane][0])      = z;
        *reinterpret_cast<uint4*>(&lds[ry][lane][WW + 4]) = z;
    }

    float acc[ND][4];
    #pragma unroll
    for (int dx = 0; dx < ND; ++dx)
        #pragma unroll
        for (int j = 0; j < 4; ++j)
            acc[dx][j] = 0.f;

    // LDS addresses (byte 16*lane based -> 16B-aligned, conflict-free).
    uint4* st0 = reinterpret_cast<uint4*>(&lds[ry][0][4 + x0]);
    uint4* st1 = reinterpret_cast<uint4*>(&lds[ry][1][4 + x0]);
    const uint4* rl0 = reinterpret_cast<const uint4*>(&lds[ry][0][x0]);
    const uint4* rr0 = reinterpret_cast<const uint4*>(&lds[ry][0][x0 + 8]);
    const uint4* rl1 = reinterpret_cast<const uint4*>(&lds[ry][1][x0]);
    const uint4* rr1 = reinterpret_cast<const uint4*>(&lds[ry][1][x0 + 8]);

    auto dotp = [&](const h2* ph, const uint4& wlu, const h2* own, const uint4& wru) {
        h2 n12[12];
        n12[0]  = as_h2(wlu.x); n12[1]  = as_h2(wlu.y);
        n12[2]  = as_h2(wlu.z); n12[3]  = as_h2(wlu.w);
        n12[4]  = own[0]; n12[5] = own[1]; n12[6] = own[2]; n12[7] = own[3];
        n12[8]  = as_h2(wru.x); n12[9]  = as_h2(wru.y);
        n12[10] = as_h2(wru.z); n12[11] = as_h2(wru.w);
        #pragma unroll
        for (int dx = 0; dx < ND; ++dx)
            #pragma unroll
            for (int j = 0; j < 4; ++j)
                acc[dx][j] = __builtin_amdgcn_fdot2(ph[j], n12[dx + j], acc[dx][j], false);
    };

    // Load one channel PAIR (4 float4 quads: prv c, c+1; nxt c, c+1).
    #define GLD(P0, P1, N0, N1) do { \
        P0 = *reinterpret_cast<const float4*>(pg); \
        P1 = *reinterpret_cast<const float4*>(pg + HW); pg += 2 * HW; \
        N0 = *reinterpret_cast<const float4*>(ng); \
        N1 = *reinterpret_cast<const float4*>(ng + HW); ng += 2 * HW; } while (0)

    #define CVTN(NH, N0, N1) do { \
        NH[0] = pk(N0.x, N1.x); NH[1] = pk(N0.y, N1.y); \
        NH[2] = pk(N0.z, N1.z); NH[3] = pk(N0.w, N1.w); } while (0)

    #define STORE4(ST, NH) do { uint4 t_; \
        t_.x = as_u32(NH[0]); t_.y = as_u32(NH[1]); \
        t_.z = as_u32(NH[2]); t_.w = as_u32(NH[3]); *(ST) = t_; } while (0)

    // One pipeline phase: read windows, stage next pair, prefetch, dot.
    #define PHASE(RL, RR, ST, NS0, NS1, NH_ST, GP0, GP1, GN0, GN1, PD0, PD1, NH_OWN) do { \
        const uint4 wl_ = *(RL); const uint4 wr_ = *(RR); \
        CVTN(NH_ST, NS0, NS1); STORE4(ST, NH_ST); \
        GLD(GP0, GP1, GN0, GN1); \
        h2 ph_[4]; \
        ph_[0] = pk(PD0.x, PD1.x); ph_[1] = pk(PD0.y, PD1.y); \
        ph_[2] = pk(PD0.z, PD1.z); ph_[3] = pk(PD0.w, PD1.w); \
        dotp(ph_, wl_, NH_OWN, wr_); \
        __threadfence_block(); } while (0)

    float4 pA0, pA1, nA0, nA1, pB0, pB1, nB0, nB1;
    float4 pC0, pC1, nC0, nC1, pD0, pD1, nD0, nD1;
    h2 nhA[4], nhB[4], nhC[4], nhD[4];

    // Prologue: pairs 0,1,2 in flight; pair 0 staged to buf0.
    GLD(pA0, pA1, nA0, nA1);
    GLD(pB0, pB1, nB0, nB1);
    GLD(pC0, pC1, nC0, nC1);
    CVTN(nhA, nA0, nA1); STORE4(st0, nhA);
    __threadfence_block();

    // 64 channel-pairs total; main loop covers pairs 0..59 (15 iters x 4).
    // Invariant entering iter at pair k: A=k, B=k+1, C=k+2 loaded;
    // buf[k&1]=pair k staged; nhA = cvt(pair k).
    for (int k = 0; k < 60; k += 4) {
        PHASE(rl0, rr0, st1, nB0, nB1, nhB, pD0, pD1, nD0, nD1, pA0, pA1, nhA);
        PHASE(rl1, rr1, st0, nC0, nC1, nhC, pA0, pA1, nA0, nA1, pB0, pB1, nhB);
        PHASE(rl0, rr0, st1, nD0, nD1, nhD, pB0, pB1, nB0, nB1, pC0, pC1, nhC);
        PHASE(rl1, rr1, st0, nA0, nA1, nhA, pC0, pC1, nC0, nC1, pD0, pD1, nhD);
    }
    // Tail: pairs 60(A),61(B),62(C),63(D). A,B,C loaded; buf0 = pair 60.
    {
        uint4 wl = *rl0, wr = *rr0;
        CVTN(nhB, nB0, nB1); STORE4(st1, nhB);
        GLD(pD0, pD1, nD0, nD1);                  // pair 63
        h2 ph[4];
        ph[0] = pk(pA0.x, pA1.x); ph[1] = pk(pA0.y, pA1.y);
        ph[2] = pk(pA0.z, pA1.z); ph[3] = pk(pA0.w, pA1.w);
        dotp(ph, wl, nhA, wr);
        __threadfence_block();

        wl = *rl1; wr = *rr1;
        CVTN(nhC, nC0, nC1); STORE4(st0, nhC);
        ph[0] = pk(pB0.x, pB1.x); ph[1] = pk(pB0.y, pB1.y);
        ph[2] = pk(pB0.z, pB1.z); ph[3] = pk(pB0.w, pB1.w);
        dotp(ph, wl, nhB, wr);
        __threadfence_block();

        wl = *rl0; wr = *rr0;
        CVTN(nhD, nD0, nD1); STORE4(st1, nhD);
        ph[0] = pk(pC0.x, pC1.x); ph[1] = pk(pC0.y, pC1.y);
        ph[2] = pk(pC0.z, pC1.z); ph[3] = pk(pC0.w, pC1.w);
        dotp(ph, wl, nhC, wr);
        __threadfence_block();

        wl = *rl1; wr = *rr1;
        ph[0] = pk(pD0.x, pD1.x); ph[1] = pk(pD0.y, pD1.y);
        ph[2] = pk(pD0.z, pD1.z); ph[3] = pk(pD0.w, pD1.w);
        dotp(ph, wl, nhD, wr);
    }
    #undef PHASE
    #undef STORE4
    #undef CVTN
    #undef GLD

    const float invc = 1.0f / (float)CC;
    #pragma unroll
    for (int dx = 0; dx < ND; ++dx) {
        const float4 o = make_float4(acc[dx][0] * invc, acc[dx][1] * invc,
                                     acc[dx][2] * invc, acc[dx][3] * invc);
        *reinterpret_cast<float4*>(outp + (size_t)dx * HW) = o;
    }
}

extern "C" void kernel_launch(void* const* d_in, const int* in_sizes, int n_in,
                              void* d_out, int out_size, void* d_ws, size_t ws_size,
                              hipStream_t stream) {
    const float* prv = (const float*)d_in[0];
    const float* nxt = (const float*)d_in[1];
    float* out = (float*)d_out;

    const int nblocks = BB * (HH / 4) * ND;  // 4 * 32 * 9 = 1152
    costvol_kernel<<<nblocks, 256, 0, stream>>>(prv, nxt, out);
}

// Round 7
// 57.499 us; speedup vs baseline: 5.5800x; 1.0022x over previous
//
#include <hip/hip_runtime.h>

// CorrelationCost (tfa), kernel_size=1, stride=1, max_displacement=pad=4,
// channels_first. B=4, C=128, H=128, W=256 -> out [4, 81, 128, 256] fp32.
//
// out[b, dy*9+dx, y, x] = (1/C) * sum_c prv[b,c,y,x] * nxt[b,c,y+dy-4,x+dx-4]
//
// R6 -> R7: still latency-bound (VALUBusy 24.7%). Two schedule fixes:
//  - LDS window reads prefetched ONE PHASE ahead of their consuming dot
//  - __threadfence_block (lgkmcnt(0) drain each phase) replaced by a
//    compiler-only fence: asm volatile("" ::: "memory"). Same-wave DS ops
//    are executed in program order by the LDS pipe; the fence only stops
//    compiler hoisting (the R3 failure mode). Compiler emits counted waits.

#define SR 4
#define ND 9          // 2*SR+1
#define BB 4
#define CC 128
#define HH 128
#define WW 256
#define HW (HH * WW)
#define PADW (WW + 8)

typedef __fp16 h2 __attribute__((ext_vector_type(2)));

static __device__ __forceinline__ h2 pk(float lo, float hi) {
    return __builtin_amdgcn_cvt_pkrtz(lo, hi);   // v_cvt_pkrtz_f16_f32
}
static __device__ __forceinline__ h2 as_h2(unsigned int u) {
    union { unsigned int u; h2 h; } v; v.u = u; return v.h;
}
static __device__ __forceinline__ unsigned int as_u32(h2 h) {
    union { unsigned int u; h2 h; } v; v.h = h; return v.u;
}

#define CFENCE asm volatile("" ::: "memory")

__global__ __launch_bounds__(256) void costvol_kernel(
    const float* __restrict__ prv,
    const float* __restrict__ nxt,
    float* __restrict__ out)
{
    // [wave][buf][padded row of half2-pairs] : 4*2*264*4 = 8448 B
    __shared__ unsigned int lds[4][2][PADW];

    // XCD-chunked bijective swizzle (1152 % 8 == 0).
    const int nwg  = gridDim.x;
    const int cpx  = nwg >> 3;
    const int orig = blockIdx.x;
    const int wid  = (orig & 7) * cpx + (orig >> 3);

    // dy fastest: the 9 dy-blocks sharing (b,y) rows are L2-local.
    const int dy = wid % ND;
    const int r  = wid / ND;
    const int y4 = r & 31;
    const int b  = r >> 5;

    const int tid  = threadIdx.x;
    const int ry   = tid >> 6;               // wave id = row within quad
    const int lane = tid & 63;
    const int x0   = lane << 2;              // 4 x-pixels per lane
    const int y    = (y4 << 2) + ry;
    const int yp   = y + dy - SR;

    float* outp = out + (((size_t)b * (ND * ND) + (size_t)dy * ND) * HH + y) * WW + x0;

    if (yp < 0 || yp >= HH) {
        const float4 z = make_float4(0.f, 0.f, 0.f, 0.f);
        #pragma unroll
        for (int dx = 0; dx < ND; ++dx)
            *reinterpret_cast<float4*>(outp + (size_t)dx * HW) = z;
        return;
    }

    const float* pg = prv + ((size_t)b * CC * HH + y)  * WW + x0;
    const float* ng = nxt + ((size_t)b * CC * HH + yp) * WW + x0;

    // Zero the 4-element pads at both ends of both buffers, once.
    if (lane < 2) {
        const uint4 z = make_uint4(0u, 0u, 0u, 0u);
        *reinterpret_cast<uint4*>(&lds[ry][lane][0])      = z;
        *reinterpret_cast<uint4*>(&lds[ry][lane][WW + 4]) = z;
    }

    float acc[ND][4];
    #pragma unroll
    for (int dx = 0; dx < ND; ++dx)
        #pragma unroll
        for (int j = 0; j < 4; ++j)
            acc[dx][j] = 0.f;

    // LDS addresses (byte 16*lane based -> 16B-aligned, conflict-free).
    uint4* st0 = reinterpret_cast<uint4*>(&lds[ry][0][4 + x0]);
    uint4* st1 = reinterpret_cast<uint4*>(&lds[ry][1][4 + x0]);
    const uint4* rl0 = reinterpret_cast<const uint4*>(&lds[ry][0][x0]);
    const uint4* rr0 = reinterpret_cast<const uint4*>(&lds[ry][0][x0 + 8]);
    const uint4* rl1 = reinterpret_cast<const uint4*>(&lds[ry][1][x0]);
    const uint4* rr1 = reinterpret_cast<const uint4*>(&lds[ry][1][x0 + 8]);

    auto dotp = [&](const h2* ph, const uint4 wlu, const h2* own, const uint4 wru) {
        h2 n12[12];
        n12[0]  = as_h2(wlu.x); n12[1]  = as_h2(wlu.y);
        n12[2]  = as_h2(wlu.z); n12[3]  = as_h2(wlu.w);
        n12[4]  = own[0]; n12[5] = own[1]; n12[6] = own[2]; n12[7] = own[3];
        n12[8]  = as_h2(wru.x); n12[9]  = as_h2(wru.y);
        n12[10] = as_h2(wru.z); n12[11] = as_h2(wru.w);
        #pragma unroll
        for (int dx = 0; dx < ND; ++dx)
            #pragma unroll
            for (int j = 0; j < 4; ++j)
                acc[dx][j] = __builtin_amdgcn_fdot2(ph[j], n12[dx + j], acc[dx][j], false);
    };

    // Load one channel PAIR (4 float4 quads: prv c,c+1; nxt c,c+1).
    #define GLD(P0, P1, N0, N1) do { \
        P0 = *reinterpret_cast<const float4*>(pg); \
        P1 = *reinterpret_cast<const float4*>(pg + HW); pg += 2 * HW; \
        N0 = *reinterpret_cast<const float4*>(ng); \
        N1 = *reinterpret_cast<const float4*>(ng + HW); ng += 2 * HW; } while (0)

    #define CVTN(NH, N0, N1) do { \
        NH[0] = pk(N0.x, N1.x); NH[1] = pk(N0.y, N1.y); \
        NH[2] = pk(N0.z, N1.z); NH[3] = pk(N0.w, N1.w); } while (0)

    #define STORE4(ST, NH) do { uint4 t_; \
        t_.x = as_u32(NH[0]); t_.y = as_u32(NH[1]); \
        t_.z = as_u32(NH[2]); t_.w = as_u32(NH[3]); *(ST) = t_; } while (0)

    #define DOT(PP0, PP1, WLC, NH_OWN, WRC) do { \
        h2 ph_[4]; \
        ph_[0] = pk(PP0.x, PP1.x); ph_[1] = pk(PP0.y, PP1.y); \
        ph_[2] = pk(PP0.z, PP1.z); ph_[3] = pk(PP0.w, PP1.w); \
        dotp(ph_, WLC, NH_OWN, WRC); } while (0)

    // One phase: stage next pair's row, prefetch global 3 ahead, then
    // (behind a compiler fence) prefetch next phase's windows, then dot
    // the CURRENT pair using windows read LAST phase.
    #define PHASE(ST, NS0, NS1, NH_ST, GP0, GP1, GN0, GN1, \
                  RL, RR, WLN, WRN, PP0, PP1, NH_OWN, WLC, WRC) do { \
        CVTN(NH_ST, NS0, NS1); STORE4(ST, NH_ST); \
        GLD(GP0, GP1, GN0, GN1); \
        CFENCE; \
        WLN = *(RL); WRN = *(RR); \
        CFENCE; \
        DOT(PP0, PP1, WLC, NH_OWN, WRC); } while (0)

    float4 pA0, pA1, nA0, nA1, pB0, pB1, nB0, nB1;
    float4 pC0, pC1, nC0, nC1, pD0, pD1, nD0, nD1;
    h2 nhA[4], nhB[4], nhC[4], nhD[4];
    uint4 wlX, wrX, wlY, wrY;

    // Prologue: pairs 0,1,2 in flight; pair 0 staged to buf0; windows(0) -> X.
    GLD(pA0, pA1, nA0, nA1);
    GLD(pB0, pB1, nB0, nB1);
    GLD(pC0, pC1, nC0, nC1);
    CVTN(nhA, nA0, nA1); STORE4(st0, nhA);
    CFENCE;
    wlX = *rl0; wrX = *rr0;
    CFENCE;

    // Invariant entering iter at pair k (k%4==0): A=k,B=k+1,C=k+2 loaded;
    // nhA = cvt(nxt pair k); windows X = pair k; buf[k&1] = pair k.
    for (int k = 0; k < 60; k += 4) {
        PHASE(st1, nB0, nB1, nhB, pD0, pD1, nD0, nD1,
              rl1, rr1, wlY, wrY, pA0, pA1, nhA, wlX, wrX);
        PHASE(st0, nC0, nC1, nhC, pA0, pA1, nA0, nA1,
              rl0, rr0, wlX, wrX, pB0, pB1, nhB, wlY, wrY);
        PHASE(st1, nD0, nD1, nhD, pB0, pB1, nB0, nB1,
              rl1, rr1, wlY, wrY, pC0, pC1, nhC, wlX, wrX);
        PHASE(st0, nA0, nA1, nhA, pC0, pC1, nC0, nC1,
              rl0, rr0, wlX, wrX, pD0, pD1, nhD, wlY, wrY);
    }
    // Tail: pairs 60(A),61(B),62(C),63(D). Windows X = pair 60; buf0 = 60.
    {
        // phase 60: loads pair 63
        CVTN(nhB, nB0, nB1); STORE4(st1, nhB);
        GLD(pD0, pD1, nD0, nD1);
        CFENCE;
        wlY = *rl1; wrY = *rr1;
        CFENCE;
        DOT(pA0, pA1, wlX, nhA, wrX);
        // phase 61
        CVTN(nhC, nC0, nC1); STORE4(st0, nhC);
        CFENCE;
        wlX = *rl0; wrX = *rr0;
        CFENCE;
        DOT(pB0, pB1, wlY, nhB, wrY);
        // phase 62
        CVTN(nhD, nD0, nD1); STORE4(st1, nhD);
        CFENCE;
        wlY = *rl1; wrY = *rr1;
        CFENCE;
        DOT(pC0, pC1, wlX, nhC, wrX);
        // phase 63
        DOT(pD0, pD1, wlY, nhD, wrY);
    }
    #undef PHASE
    #undef DOT
    #undef STORE4
    #undef CVTN
    #undef GLD

    const float invc = 1.0f / (float)CC;
    #pragma unroll
    for (int dx = 0; dx < ND; ++dx) {
        const float4 o = make_float4(acc[dx][0] * invc, acc[dx][1] * invc,
                                     acc[dx][2] * invc, acc[dx][3] * invc);
        *reinterpret_cast<float4*>(outp + (size_t)dx * HW) = o;
    }
}

extern "C" void kernel_launch(void* const* d_in, const int* in_sizes, int n_in,
                              void* d_out, int out_size, void* d_ws, size_t ws_size,
                              hipStream_t stream) {
    const float* prv = (const float*)d_in[0];
    const float* nxt = (const float*)d_in[1];
    float* out = (float*)d_out;

    const int nblocks = BB * (HH / 4) * ND;  // 4 * 32 * 9 = 1152
    costvol_kernel<<<nblocks, 256, 0, stream>>>(prv, nxt, out);
}

// Round 8
// 56.545 us; speedup vs baseline: 5.6742x; 1.0169x over previous
//
#include <hip/hip_runtime.h>

// CorrelationCost (tfa), kernel_size=1, stride=1, max_displacement=pad=4,
// channels_first. B=4, C=128, H=128, W=256 -> out [4, 81, 128, 256] fp32.
//
// out[b, dy*9+dx, y, x] = (1/C) * sum_c prv[b,c,y,x] * nxt[b,c,y+dy-4,x+dx-4]
//
// R7 -> R8: occupancy-starved (25%, grid 1152 = 4.5 blocks/CU vs 7 allowed).
// Split channels across waves: block = (b, y-pair, dy); 4 waves = 2 rows x
// 2 channel-halves (32 pairs each). Grid 2304 -> 9 blocks/CU requested.
// Main loop = R7's dot2 pipeline (32 phases). Epilogue: c-half partials
// reduced via LDS (union'd with staging), two __syncthreads().

#define SR 4
#define ND 9          // 2*SR+1
#define BB 4
#define CC 128
#define HH 128
#define WW 256
#define HW (HH * WW)
#define PADW (WW + 8)  // 264

typedef __fp16 h2 __attribute__((ext_vector_type(2)));

static __device__ __forceinline__ h2 pk(float lo, float hi) {
    return __builtin_amdgcn_cvt_pkrtz(lo, hi);   // v_cvt_pkrtz_f16_f32
}
static __device__ __forceinline__ h2 as_h2(unsigned int u) {
    union { unsigned int u; h2 h; } v; v.u = u; return v.h;
}
static __device__ __forceinline__ unsigned int as_u32(h2 h) {
    union { unsigned int u; h2 h; } v; v.h = h; return v.u;
}

#define CFENCE asm volatile("" ::: "memory")

__global__ __launch_bounds__(256) void costvol_kernel(
    const float* __restrict__ prv,
    const float* __restrict__ nxt,
    float* __restrict__ out)
{
    // Union: staging (4 waves x 2 bufs x 264 uints = 2112) lives in the
    // same space as the reduction area (2 rows x 64 lanes x 36 floats =
    // 4608 uints = 18432 B). Staging is dead before reduction starts.
    __shared__ __align__(16) unsigned int shraw[2 * 64 * 36];

    // XCD-chunked bijective swizzle (2304 % 8 == 0).
    const int nwg  = gridDim.x;
    const int cpx  = nwg >> 3;
    const int orig = blockIdx.x;
    const int wid  = (orig & 7) * cpx + (orig >> 3);

    // dy fastest: the 9 dy-blocks sharing (b,y-pair) rows are L2-local.
    const int dy  = wid % ND;
    const int r   = wid / ND;
    const int yp2 = r & 63;                  // y-pair index
    const int b   = r >> 6;

    const int tid  = threadIdx.x;
    const int w    = tid >> 6;               // wave 0..3
    const int lane = tid & 63;
    const int ry   = w & 1;                  // row within pair
    const int ch   = w >> 1;                 // channel half
    const int x0   = lane << 2;              // 4 x-pixels per lane
    const int y    = (yp2 << 1) + ry;
    const int yq   = y + dy - SR;            // nxt source row
    const int c0   = ch << 6;                // 0 or 64

    const bool valid = (yq >= 0) && (yq < HH);

    float acc[ND][4];
    #pragma unroll
    for (int dx = 0; dx < ND; ++dx)
        #pragma unroll
        for (int j = 0; j < 4; ++j)
            acc[dx][j] = 0.f;

    if (valid) {
        const float* pg = prv + ((size_t)(b * CC + c0)) * HW + y  * WW + x0;
        const float* ng = nxt + ((size_t)(b * CC + c0)) * HW + yq * WW + x0;

        unsigned int* stage = shraw + w * (2 * PADW);

        // Zero the 4-element pads at both ends of both buffers, once.
        if (lane < 2) {
            const uint4 z = make_uint4(0u, 0u, 0u, 0u);
            *reinterpret_cast<uint4*>(stage + lane * PADW)          = z;
            *reinterpret_cast<uint4*>(stage + lane * PADW + WW + 4) = z;
        }

        unsigned int* st0 = stage + 0 * PADW + 4 + x0;
        unsigned int* st1 = stage + 1 * PADW + 4 + x0;
        const uint4* rl0 = reinterpret_cast<const uint4*>(stage + 0 * PADW + x0);
        const uint4* rr0 = reinterpret_cast<const uint4*>(stage + 0 * PADW + x0 + 8);
        const uint4* rl1 = reinterpret_cast<const uint4*>(stage + 1 * PADW + x0);
        const uint4* rr1 = reinterpret_cast<const uint4*>(stage + 1 * PADW + x0 + 8);

        auto dotp = [&](const h2* ph, const uint4 wlu, const h2* own, const uint4 wru) {
            h2 n12[12];
            n12[0]  = as_h2(wlu.x); n12[1]  = as_h2(wlu.y);
            n12[2]  = as_h2(wlu.z); n12[3]  = as_h2(wlu.w);
            n12[4]  = own[0]; n12[5] = own[1]; n12[6] = own[2]; n12[7] = own[3];
            n12[8]  = as_h2(wru.x); n12[9]  = as_h2(wru.y);
            n12[10] = as_h2(wru.z); n12[11] = as_h2(wru.w);
            #pragma unroll
            for (int dx = 0; dx < ND; ++dx)
                #pragma unroll
                for (int j = 0; j < 4; ++j)
                    acc[dx][j] = __builtin_amdgcn_fdot2(ph[j], n12[dx + j], acc[dx][j], false);
        };

        #define GLD(P0, P1, N0, N1) do { \
            P0 = *reinterpret_cast<const float4*>(pg); \
            P1 = *reinterpret_cast<const float4*>(pg + HW); pg += 2 * HW; \
            N0 = *reinterpret_cast<const float4*>(ng); \
            N1 = *reinterpret_cast<const float4*>(ng + HW); ng += 2 * HW; } while (0)

        #define CVTN(NH, N0, N1) do { \
            NH[0] = pk(N0.x, N1.x); NH[1] = pk(N0.y, N1.y); \
            NH[2] = pk(N0.z, N1.z); NH[3] = pk(N0.w, N1.w); } while (0)

        #define STORE4(ST, NH) do { uint4 t_; \
            t_.x = as_u32(NH[0]); t_.y = as_u32(NH[1]); \
            t_.z = as_u32(NH[2]); t_.w = as_u32(NH[3]); \
            *reinterpret_cast<uint4*>(ST) = t_; } while (0)

        #define DOT(PP0, PP1, WLC, NH_OWN, WRC) do { \
            h2 ph_[4]; \
            ph_[0] = pk(PP0.x, PP1.x); ph_[1] = pk(PP0.y, PP1.y); \
            ph_[2] = pk(PP0.z, PP1.z); ph_[3] = pk(PP0.w, PP1.w); \
            dotp(ph_, WLC, NH_OWN, WRC); } while (0)

        #define PHASE(ST, NS0, NS1, NH_ST, GP0, GP1, GN0, GN1, \
                      RL, RR, WLN, WRN, PP0, PP1, NH_OWN, WLC, WRC) do { \
            CVTN(NH_ST, NS0, NS1); STORE4(ST, NH_ST); \
            GLD(GP0, GP1, GN0, GN1); \
            CFENCE; \
            WLN = *(RL); WRN = *(RR); \
            CFENCE; \
            DOT(PP0, PP1, WLC, NH_OWN, WRC); } while (0)

        float4 pA0, pA1, nA0, nA1, pB0, pB1, nB0, nB1;
        float4 pC0, pC1, nC0, nC1, pD0, pD1, nD0, nD1;
        h2 nhA[4], nhB[4], nhC[4], nhD[4];
        uint4 wlX, wrX, wlY, wrY;

        // Prologue: pairs 0,1,2 in flight; pair 0 staged; windows(0) -> X.
        GLD(pA0, pA1, nA0, nA1);
        GLD(pB0, pB1, nB0, nB1);
        GLD(pC0, pC1, nC0, nC1);
        CVTN(nhA, nA0, nA1); STORE4(st0, nhA);
        CFENCE;
        wlX = *rl0; wrX = *rr0;
        CFENCE;

        // 32 channel-pairs: 7 iters x 4 phases + 4-phase tail.
        for (int k = 0; k < 28; k += 4) {
            PHASE(st1, nB0, nB1, nhB, pD0, pD1, nD0, nD1,
                  rl1, rr1, wlY, wrY, pA0, pA1, nhA, wlX, wrX);
            PHASE(st0, nC0, nC1, nhC, pA0, pA1, nA0, nA1,
                  rl0, rr0, wlX, wrX, pB0, pB1, nhB, wlY, wrY);
            PHASE(st1, nD0, nD1, nhD, pB0, pB1, nB0, nB1,
                  rl1, rr1, wlY, wrY, pC0, pC1, nhC, wlX, wrX);
            PHASE(st0, nA0, nA1, nhA, pC0, pC1, nC0, nC1,
                  rl0, rr0, wlX, wrX, pD0, pD1, nhD, wlY, wrY);
        }
        // Tail: pairs 28(A),29(B),30(C),31(D). Windows X = 28; buf0 = 28.
        {
            CVTN(nhB, nB0, nB1); STORE4(st1, nhB);
            GLD(pD0, pD1, nD0, nD1);                  // pair 31
            CFENCE;
            wlY = *rl1; wrY = *rr1;
            CFENCE;
            DOT(pA0, pA1, wlX, nhA, wrX);

            CVTN(nhC, nC0, nC1); STORE4(st0, nhC);
            CFENCE;
            wlX = *rl0; wrX = *rr0;
            CFENCE;
            DOT(pB0, pB1, wlY, nhB, wrY);

            CVTN(nhD, nD0, nD1); STORE4(st1, nhD);
            CFENCE;
            wlY = *rl1; wrY = *rr1;
            CFENCE;
            DOT(pC0, pC1, wlX, nhC, wrX);

            DOT(pD0, pD1, wlY, nhD, wrY);
        }
        #undef PHASE
        #undef DOT
        #undef STORE4
        #undef CVTN
        #undef GLD
    }

    // Cross-wave channel reduction. All threads reach both barriers.
    __syncthreads();
    if (ch == 1) {
        float* red = reinterpret_cast<float*>(shraw) + ry * (64 * 36) + lane * 36;
        #pragma unroll
        for (int dx = 0; dx < ND; ++dx) {
            float4 t = make_float4(acc[dx][0], acc[dx][1], acc[dx][2], acc[dx][3]);
            *reinterpret_cast<float4*>(red + dx * 4) = t;
        }
    }
    __syncthreads();
    if (ch == 0) {
        const float* red = reinterpret_cast<const float*>(shraw) + ry * (64 * 36) + lane * 36;
        float* outp = out + (((size_t)b * (ND * ND) + (size_t)dy * ND) * HH + y) * WW + x0;
        const float invc = 1.0f / (float)CC;
        #pragma unroll
        for (int dx = 0; dx < ND; ++dx) {
            const float4 t = *reinterpret_cast<const float4*>(red + dx * 4);
            float4 o;
            o.x = (acc[dx][0] + t.x) * invc;
            o.y = (acc[dx][1] + t.y) * invc;
            o.z = (acc[dx][2] + t.z) * invc;
            o.w = (acc[dx][3] + t.w) * invc;
            *reinterpret_cast<float4*>(outp + (size_t)dx * HW) = o;
        }
    }
}

extern "C" void kernel_launch(void* const* d_in, const int* in_sizes, int n_in,
                              void* d_out, int out_size, void* d_ws, size_t ws_size,
                              hipStream_t stream) {
    const float* prv = (const float*)d_in[0];
    const float* nxt = (const float*)d_in[1];
    float* out = (float*)d_out;

    const int nblocks = BB * (HH / 2) * ND;  // 4 * 64 * 9 = 2304
    costvol_kernel<<<nblocks, 256, 0, stream>>>(prv, nxt, out);
}